// Round 2
// baseline (110.195 us; speedup 1.0000x reference)
//
#include <hip/hip_runtime.h>
#include <math.h>

#ifndef __has_builtin
#define __has_builtin(x) 0
#endif

__device__ __forceinline__ float fast_exp2(float x) {
#if __has_builtin(__builtin_amdgcn_exp2f)
    return __builtin_amdgcn_exp2f(x);   // raw v_exp_f32
#else
    return exp2f(x);
#endif
}

// ---------------------------------------------------------------------------
// Kernel 1: pack per-node constants: {px, py, s, w0, w1, w2, 0, 0} (32 B/node)
// s = -log2(e)/2 / sigmaSq  so that rbf = exp2(Dsq * s) == exp(-Dsq/(2 sigmaSq))
// ---------------------------------------------------------------------------
__global__ void pack_nodes(const int* __restrict__ pat, const float* __restrict__ W2,
                           const float* __restrict__ sigmaSq, float* __restrict__ nodes,
                           int P) {
    int p = blockIdx.x * blockDim.x + threadIdx.x;
    if (p >= P) return;
    float* q = nodes + 8 * (size_t)p;
    q[0] = (float)pat[2 * p];
    q[1] = (float)pat[2 * p + 1];
    q[2] = -0.7213475204444817f / sigmaSq[p];   // -log2(e)/2 / sigma^2
    q[3] = W2[p];            // W2 is (C,P) row-major
    q[4] = W2[P + p];
    q[5] = W2[2 * P + p];
    q[6] = 0.0f;
    q[7] = 0.0f;
}

// ---------------------------------------------------------------------------
// Kernel 2: main RBF loop. NQ queries per thread (independent dep chains to
// hide s_load/exp latency); wave-uniform node index so node data arrives via
// the scalar pipe (s_load, 0 VALU cost). Writes float4 partials {den,a0,a1,a2}.
// ---------------------------------------------------------------------------
template <int PCHUNK, int NQ>
__global__ __launch_bounds__(256) void rbf_main_nq(const int* __restrict__ X,
                                                   const float* __restrict__ nodes,
                                                   float4* __restrict__ part, int N) {
    const int tid = threadIdx.x;
    const int pc  = blockIdx.y;
    const int n0  = blockIdx.x * (256 * NQ) + tid;
    const float* __restrict__ q = nodes + (size_t)pc * PCHUNK * 8;

    float xn[NQ], yn[NQ];
    float4 acc[NQ];
#pragma unroll
    for (int k = 0; k < NQ; ++k) {
        int2 xi = ((const int2*)X)[n0 + k * 256];
        xn[k] = (float)xi.x;
        yn[k] = (float)xi.y;
        acc[k] = make_float4(0.f, 0.f, 0.f, 0.f);
    }

#pragma unroll 4
    for (int j = 0; j < PCHUNK; ++j) {
        float px = q[j * 8 + 0];
        float py = q[j * 8 + 1];
        float s  = q[j * 8 + 2];
        float w0 = q[j * 8 + 3];
        float w1 = q[j * 8 + 4];
        float w2 = q[j * 8 + 5];
#pragma unroll
        for (int k = 0; k < NQ; ++k) {
            float dx = xn[k] - px;
            float dy = yn[k] - py;
            float r  = fast_exp2(fmaf(dy, dy, dx * dx) * s);
            acc[k].x += r;
            acc[k].y = fmaf(r, w0, acc[k].y);
            acc[k].z = fmaf(r, w1, acc[k].z);
            acc[k].w = fmaf(r, w2, acc[k].w);
        }
    }

#pragma unroll
    for (int k = 0; k < NQ; ++k)
        part[(size_t)pc * N + n0 + k * 256] = acc[k];
}

// Generic (runtime-P) fallback, non-split — only used if sizes are unexpected.
__global__ __launch_bounds__(256) void rbf_main_dyn(const int* __restrict__ X,
                                                    const float* __restrict__ nodes,
                                                    float* __restrict__ outp,
                                                    int N, int P) {
    int n = blockIdx.x * 256 + threadIdx.x;
    if (n >= N) return;
    float xn = (float)X[2 * n], yn = (float)X[2 * n + 1];
    float den = 0.f, a0 = 0.f, a1 = 0.f, a2 = 0.f;
    for (int j = 0; j < P; ++j) {
        const float* q = nodes + (size_t)j * 8;
        float dx = xn - q[0], dy = yn - q[1];
        float r = fast_exp2(fmaf(dy, dy, dx * dx) * q[2]);
        den += r;
        a0 = fmaf(r, q[3], a0);
        a1 = fmaf(r, q[4], a1);
        a2 = fmaf(r, q[5], a2);
    }
    outp[3 * n + 0] = a0 / den;
    outp[3 * n + 1] = a1 / den;
    outp[3 * n + 2] = a2 / den;
}

// ---------------------------------------------------------------------------
// Kernel 3: reduce the PSPLIT partials and divide.
// ---------------------------------------------------------------------------
__global__ __launch_bounds__(256) void rbf_reduce(const float4* __restrict__ part,
                                                  float* __restrict__ out,
                                                  int N, int psplit) {
    int n = blockIdx.x * 256 + threadIdx.x;
    if (n >= N) return;
    float den = 0.f, a0 = 0.f, a1 = 0.f, a2 = 0.f;
    for (int pc = 0; pc < psplit; ++pc) {
        float4 v = part[(size_t)pc * N + n];
        den += v.x; a0 += v.y; a1 += v.z; a2 += v.w;
    }
    out[3 * n + 0] = a0 / den;
    out[3 * n + 1] = a1 / den;
    out[3 * n + 2] = a2 / den;
}

extern "C" void kernel_launch(void* const* d_in, const int* in_sizes, int n_in,
                              void* d_out, int out_size, void* d_ws, size_t ws_size,
                              hipStream_t stream) {
    const int*   X    = (const int*)d_in[0];
    const int*   pat  = (const int*)d_in[1];
    const float* W2   = (const float*)d_in[2];
    const float* sig  = (const float*)d_in[3];
    float*       out  = (float*)d_out;

    const int N = in_sizes[0] / 2;     // 65536
    const int P = in_sizes[3];         // 2048

    float* nodes = (float*)d_ws;
    size_t nodes_bytes = (size_t)P * 8 * sizeof(float);

    pack_nodes<<<dim3((P + 255) / 256), dim3(256), 0, stream>>>(pat, W2, sig, nodes, P);

    float4* part = (float4*)(nodes + (size_t)P * 8);   // 64 KB in, 16 B aligned

    // Preferred: PSPLIT=16, NQ=4 -> 1024 WGs (4/CU, 16 waves/CU), 4-way ILP.
    size_t need16 = nodes_bytes + (size_t)16 * N * sizeof(float4);
    size_t need8  = nodes_bytes + (size_t)8  * N * sizeof(float4);

    if (P == 2048 && N % 1024 == 0 && ws_size >= need16) {
        dim3 grid(N / 1024, 16);
        rbf_main_nq<128, 4><<<grid, dim3(256), 0, stream>>>(X, nodes, part, N);
        rbf_reduce<<<dim3((N + 255) / 256), dim3(256), 0, stream>>>(part, out, N, 16);
    } else if (P == 2048 && N % 512 == 0 && ws_size >= need8) {
        dim3 grid(N / 512, 8);
        rbf_main_nq<256, 2><<<grid, dim3(256), 0, stream>>>(X, nodes, part, N);
        rbf_reduce<<<dim3((N + 255) / 256), dim3(256), 0, stream>>>(part, out, N, 8);
    } else {
        rbf_main_dyn<<<dim3((N + 255) / 256), dim3(256), 0, stream>>>(X, nodes, out, N, P);
    }
}

// Round 3
// 100.957 us; speedup vs baseline: 1.0915x; 1.0915x over previous
//
#include <hip/hip_runtime.h>
#include <math.h>

#ifndef __has_builtin
#define __has_builtin(x) 0
#endif

typedef float v2f __attribute__((ext_vector_type(2)));

__device__ __forceinline__ v2f splat2(float x) { v2f v; v.x = x; v.y = x; return v; }

__device__ __forceinline__ float fast_exp2(float x) {
#if __has_builtin(__builtin_amdgcn_exp2f)
    return __builtin_amdgcn_exp2f(x);   // raw v_exp_f32
#else
    return exp2f(x);
#endif
}

// ---------------------------------------------------------------------------
// Kernel 1: pack per-node constants: {px, py, s, w0, w1, w2, 0, 0} (32 B/node)
// s = -log2(e)/2 / sigmaSq  so that rbf = exp2(Dsq * s) == exp(-Dsq/(2 sigmaSq))
// ---------------------------------------------------------------------------
__global__ void pack_nodes(const int* __restrict__ pat, const float* __restrict__ W2,
                           const float* __restrict__ sigmaSq, float* __restrict__ nodes,
                           int P) {
    int p = blockIdx.x * blockDim.x + threadIdx.x;
    if (p >= P) return;
    float* q = nodes + 8 * (size_t)p;
    q[0] = (float)pat[2 * p];
    q[1] = (float)pat[2 * p + 1];
    q[2] = -0.7213475204444817f / sigmaSq[p];   // -log2(e)/2 / sigma^2
    q[3] = W2[p];            // W2 is (C,P) row-major
    q[4] = W2[P + p];
    q[5] = W2[2 * P + p];
    q[6] = 0.0f;
    q[7] = 0.0f;
}

// ---------------------------------------------------------------------------
// Kernel 2: main RBF loop, packed-fp32 version. Two queries share one v2f
// lane-pair so subtract/square/scale/accumulate become v_pk_* (2 fp32 per
// issue). Node data arrives wave-uniform via the scalar pipe (s_load).
// NQ2 = pairs of queries per thread (total queries/thread = 2*NQ2).
// Writes float4 partials {den, a0, a1, a2} per (pc, n).
// ---------------------------------------------------------------------------
template <int PCHUNK, int NQ2>
__global__ __launch_bounds__(256) void rbf_main_pk(const int* __restrict__ X,
                                                   const float* __restrict__ nodes,
                                                   float4* __restrict__ part, int N) {
    const int tid = threadIdx.x;
    const int pc  = blockIdx.y;
    const int n0  = blockIdx.x * (256 * 2 * NQ2) + tid;
    const float* __restrict__ q = nodes + (size_t)pc * PCHUNK * 8;

    v2f xn[NQ2], yn[NQ2], den[NQ2], a0[NQ2], a1[NQ2], a2[NQ2];
#pragma unroll
    for (int g = 0; g < NQ2; ++g) {
        int2 xi0 = ((const int2*)X)[n0 + (2 * g) * 256];
        int2 xi1 = ((const int2*)X)[n0 + (2 * g + 1) * 256];
        v2f xv; xv.x = (float)xi0.x; xv.y = (float)xi1.x;
        v2f yv; yv.x = (float)xi0.y; yv.y = (float)xi1.y;
        xn[g] = xv; yn[g] = yv;
        den[g] = splat2(0.f); a0[g] = splat2(0.f);
        a1[g] = splat2(0.f);  a2[g] = splat2(0.f);
    }

#pragma unroll 4
    for (int j = 0; j < PCHUNK; ++j) {
        float px = q[j * 8 + 0];
        float py = q[j * 8 + 1];
        float s  = q[j * 8 + 2];
        float w0 = q[j * 8 + 3];
        float w1 = q[j * 8 + 4];
        float w2 = q[j * 8 + 5];
#pragma unroll
        for (int g = 0; g < NQ2; ++g) {
            v2f dx = xn[g] - splat2(px);
            v2f dy = yn[g] - splat2(py);
            // exact integer-valued distance, one rounding at *s (same as R0/R1)
            v2f d2  = dx * dx + dy * dy;     // contracted -> v_pk_fma
            v2f arg = d2 * splat2(s);
            v2f r;
            r.x = fast_exp2(arg.x);
            r.y = fast_exp2(arg.y);
            den[g] += r;
            a0[g] += r * splat2(w0);         // contracted -> v_pk_fma
            a1[g] += r * splat2(w1);
            a2[g] += r * splat2(w2);
        }
    }

#pragma unroll
    for (int g = 0; g < NQ2; ++g) {
        part[(size_t)pc * N + n0 + (2 * g) * 256] =
            make_float4(den[g].x, a0[g].x, a1[g].x, a2[g].x);
        part[(size_t)pc * N + n0 + (2 * g + 1) * 256] =
            make_float4(den[g].y, a0[g].y, a1[g].y, a2[g].y);
    }
}

// Generic (runtime-P) fallback, non-split — only used if sizes are unexpected.
__global__ __launch_bounds__(256) void rbf_main_dyn(const int* __restrict__ X,
                                                    const float* __restrict__ nodes,
                                                    float* __restrict__ outp,
                                                    int N, int P) {
    int n = blockIdx.x * 256 + threadIdx.x;
    if (n >= N) return;
    float xn = (float)X[2 * n], yn = (float)X[2 * n + 1];
    float den = 0.f, a0 = 0.f, a1 = 0.f, a2 = 0.f;
    for (int j = 0; j < P; ++j) {
        const float* q = nodes + (size_t)j * 8;
        float dx = xn - q[0], dy = yn - q[1];
        float r = fast_exp2(fmaf(dy, dy, dx * dx) * q[2]);
        den += r;
        a0 = fmaf(r, q[3], a0);
        a1 = fmaf(r, q[4], a1);
        a2 = fmaf(r, q[5], a2);
    }
    outp[3 * n + 0] = a0 / den;
    outp[3 * n + 1] = a1 / den;
    outp[3 * n + 2] = a2 / den;
}

// ---------------------------------------------------------------------------
// Kernel 3: reduce the PSPLIT partials and divide.
// ---------------------------------------------------------------------------
__global__ __launch_bounds__(256) void rbf_reduce(const float4* __restrict__ part,
                                                  float* __restrict__ out,
                                                  int N, int psplit) {
    int n = blockIdx.x * 256 + threadIdx.x;
    if (n >= N) return;
    float den = 0.f, a0 = 0.f, a1 = 0.f, a2 = 0.f;
#pragma unroll 8
    for (int pc = 0; pc < psplit; ++pc) {
        float4 v = part[(size_t)pc * N + n];
        den += v.x; a0 += v.y; a1 += v.z; a2 += v.w;
    }
    out[3 * n + 0] = a0 / den;
    out[3 * n + 1] = a1 / den;
    out[3 * n + 2] = a2 / den;
}

extern "C" void kernel_launch(void* const* d_in, const int* in_sizes, int n_in,
                              void* d_out, int out_size, void* d_ws, size_t ws_size,
                              hipStream_t stream) {
    const int*   X    = (const int*)d_in[0];
    const int*   pat  = (const int*)d_in[1];
    const float* W2   = (const float*)d_in[2];
    const float* sig  = (const float*)d_in[3];
    float*       out  = (float*)d_out;

    const int N = in_sizes[0] / 2;     // 65536
    const int P = in_sizes[3];         // 2048

    float* nodes = (float*)d_ws;
    size_t nodes_bytes = (size_t)P * 8 * sizeof(float);

    pack_nodes<<<dim3((P + 255) / 256), dim3(256), 0, stream>>>(pat, W2, sig, nodes, P);

    float4* part = (float4*)(nodes + (size_t)P * 8);   // 64 KB in, 16 B aligned

    size_t need32 = nodes_bytes + (size_t)32 * N * sizeof(float4);
    size_t need16 = nodes_bytes + (size_t)16 * N * sizeof(float4);
    size_t need8  = nodes_bytes + (size_t)8  * N * sizeof(float4);

    if (P == 2048 && N % 1024 == 0 && ws_size >= need32) {
        // 2048 WGs (8/CU, 8 waves/SIMD), 4 queries/thread packed as 2x v2f
        dim3 grid(N / 1024, 32);
        rbf_main_pk<64, 2><<<grid, dim3(256), 0, stream>>>(X, nodes, part, N);
        rbf_reduce<<<dim3((N + 255) / 256), dim3(256), 0, stream>>>(part, out, N, 32);
    } else if (P == 2048 && N % 1024 == 0 && ws_size >= need16) {
        dim3 grid(N / 1024, 16);
        rbf_main_pk<128, 2><<<grid, dim3(256), 0, stream>>>(X, nodes, part, N);
        rbf_reduce<<<dim3((N + 255) / 256), dim3(256), 0, stream>>>(part, out, N, 16);
    } else if (P == 2048 && N % 512 == 0 && ws_size >= need8) {
        dim3 grid(N / 512, 8);
        rbf_main_pk<256, 1><<<grid, dim3(256), 0, stream>>>(X, nodes, part, N);
        rbf_reduce<<<dim3((N + 255) / 256), dim3(256), 0, stream>>>(part, out, N, 8);
    } else {
        rbf_main_dyn<<<dim3((N + 255) / 256), dim3(256), 0, stream>>>(X, nodes, out, N, P);
    }
}